// Round 1
// baseline (826.430 us; speedup 1.0000x reference)
//
#include <hip/hip_runtime.h>
#include <math.h>

#define MM 512
#define KK 100000
#define NB1 1024               // blocks in pass kernels / fused kernel
#define NW  (NB1 * 4)          // total waves in pass phases
#define NOUT 16                // k_out blocks

// ws float layout:
// [0..512)     v = W^T a1
// [512..1024)  u = W^T a2
// [1024]       sumU = sum_i x_i . u
// [1025]       Z    = sum_i exp(relu(s_i+c)-m) (atomic-accumulated, /64)
// [1026]       done-counter for k_out (int)
// [1027..1030) grid-barrier counters bar0/barA/barB (int)
// [1536..2048) acc (k_out cross-block accumulator)
// [2048..3072) pmax (per-block partial max of s)
// [4096..+KK)  s    (s_i = x_i . v)
// [131072..655360) part: per-block unnormalized colsums, part[b][512]
// memset zeroes the first 2048 floats (v,u,sumU,Z,cnt,bars,acc).

__device__ inline float waveSum(float v){
  #pragma unroll
  for(int off = 32; off > 0; off >>= 1) v += __shfl_down(v, off, 64);
  return v;
}
__device__ inline float waveMax(float v){
  #pragma unroll
  for(int off = 32; off > 0; off >>= 1) v = fmaxf(v, __shfl_down(v, off, 64));
  return v;
}
__device__ inline float dot8(float4 x0, float4 x1, float4 v0, float4 v1){
  return x0.x*v0.x + x0.y*v0.y + x0.z*v0.z + x0.w*v0.w
       + x1.x*v1.x + x1.y*v1.y + x1.z*v1.z + x1.w*v1.w;
}

// Device-wide barrier: arrive (release) + spin (acquire). Safe only under
// cooperative launch (all NB1 blocks co-resident).
__device__ inline void gridBarrier(int* bar, int tid){
  __syncthreads();
  if(tid == 0){
    __threadfence();                 // release: flush this block's writes
    atomicAdd(bar, 1);
    while(__hip_atomic_load(bar, __ATOMIC_ACQUIRE, __HIP_MEMORY_SCOPE_AGENT) < NB1)
      __builtin_amdgcn_s_sleep(16);
    __threadfence();                 // acquire: invalidate stale cache lines
  }
  __syncthreads();
}

// ---------------------------------------------------------------------------
// Fused cooperative kernel: phase0 (v,u) -> phase1 (s, sumU, pmax) ->
// phase2 (weighted colsums -> part, Z) -> phase3 (reduce -> out).
// __launch_bounds__(256,4): <=128 VGPR, 4 blocks/CU -> 1024 blocks co-resident.
// ---------------------------------------------------------------------------
__global__ __launch_bounds__(256, 4)
void k_fused(const float* __restrict__ x, const float* __restrict__ W,
             const float* __restrict__ bb_, const float* __restrict__ a,
             float* __restrict__ ws, float* __restrict__ out){
  float* v    = ws;
  float* u    = ws + 512;
  float* sumU = ws + 1024;
  float* Z    = ws + 1025;
  int*   cnt  = (int*)(ws + 1026);
  int*   bar0 = (int*)(ws + 1027);
  int*   barA = (int*)(ws + 1028);
  int*   barB = (int*)(ws + 1029);
  float* acc  = ws + 1536;
  float* pmax = ws + 2048;
  float* s    = ws + 4096;
  float* part = ws + 131072;

  __shared__ float red[8];
  __shared__ float lw[2048];       // 4 waves x 64 lanes x 8 cols (8 KB)
  __shared__ int lastf;

  int tid  = threadIdx.x;
  int lane = tid & 63;
  int wid  = tid >> 6;
  int gw   = blockIdx.x * 4 + wid;

  // ---- phase 0: v_j = sum_k W[k,j] a1[k]; u_j = sum_k W[k,j] a2[k] ----
  if(blockIdx.x < 64){
    int j  = tid;
    int k0 = blockIdx.x * 8;
    float pv0 = 0.f, pu0 = 0.f, pv1 = 0.f, pu1 = 0.f;
    #pragma unroll
    for(int kk = 0; kk < 8; kk++){
      float a1v = a[k0 + kk], a2v = a[MM + k0 + kk];
      float w0 = W[(size_t)(k0 + kk) * MM + j];
      float w1 = W[(size_t)(k0 + kk) * MM + j + 256];
      pv0 += w0 * a1v; pu0 += w0 * a2v;
      pv1 += w1 * a1v; pu1 += w1 * a2v;
    }
    atomicAdd(&v[j], pv0);       atomicAdd(&u[j], pu0);
    atomicAdd(&v[j + 256], pv1); atomicAdd(&u[j + 256], pu1);
  }
  gridBarrier(bar0, tid);

  // ---- phase 1: s_i = x_i.v (8-row batched butterfly), sumU, per-block max ----
  {
    const float4* v4 = (const float4*)v;
    const float4* u4 = (const float4*)u;
    float4 v0 = v4[lane], v1 = v4[64 + lane];
    float4 u0 = u4[lane], u1 = u4[64 + lane];
    float accU = 0.f;
    float wmax = -3.4e38f;

    int myN = (KK - 1 - gw) / NW + 1;
    int k = 0;
    for(; k + 8 <= myN; k += 8){
      float d[8];
      #pragma unroll
      for(int r = 0; r < 8; r++){
        size_t row = (size_t)gw + (size_t)(k + r) * NW;
        const float4* xr = (const float4*)(x + row * MM);
        float4 x0 = xr[lane];
        float4 x1 = xr[64 + lane];
        d[r]  = dot8(x0, x1, v0, v1);
        accU += dot8(x0, x1, u0, u1);
      }
      #pragma unroll
      for(int off = 1; off < 64; off <<= 1){
        #pragma unroll
        for(int r = 0; r < 8; r++) d[r] += __shfl_xor(d[r], off, 64);
      }
      float m01 = fmaxf(fmaxf(d[0], d[1]), fmaxf(d[2], d[3]));
      float m23 = fmaxf(fmaxf(d[4], d[5]), fmaxf(d[6], d[7]));
      wmax = fmaxf(wmax, fmaxf(m01, m23));
      float s0 = (lane & 1) ? d[1] : d[0];
      float s1 = (lane & 1) ? d[3] : d[2];
      float s2 = (lane & 1) ? d[5] : d[4];
      float s3 = (lane & 1) ? d[7] : d[6];
      float t0 = (lane & 2) ? s1 : s0;
      float t1 = (lane & 2) ? s3 : s2;
      float rr = (lane & 4) ? t1 : t0;
      if(lane < 8) s[(size_t)gw + (size_t)(k + lane) * NW] = rr;
    }
    for(; k < myN; k++){
      size_t row = (size_t)gw + (size_t)k * NW;
      const float4* xr = (const float4*)(x + row * MM);
      float4 x0 = xr[lane];
      float4 x1 = xr[64 + lane];
      float d = dot8(x0, x1, v0, v1);
      accU += dot8(x0, x1, u0, u1);
      #pragma unroll
      for(int off = 1; off < 64; off <<= 1) d += __shfl_xor(d, off, 64);
      wmax = fmaxf(wmax, d);
      if(lane == 0) s[row] = d;
    }

    float ws_ = waveSum(accU);
    if(lane == 0){ red[wid] = ws_; red[4 + wid] = wmax; }
    __syncthreads();
    if(tid == 0){
      atomicAdd(sumU, red[0] + red[1] + red[2] + red[3]);
      pmax[blockIdx.x] = fmaxf(fmaxf(red[4], red[5]), fmaxf(red[6], red[7]));
    }
  }
  gridBarrier(barA, tid);

  // ---- phase 2: c,m; stream rows; per-block colsum partials; Z ----
  {
    float tp = bb_[tid]       * (a[tid]       + a[MM + tid])
             + bb_[tid + 256] * (a[tid + 256] + a[MM + tid + 256]);
    float mx = fmaxf(fmaxf(pmax[tid], pmax[tid + 256]),
                     fmaxf(pmax[tid + 512], pmax[tid + 768]));
    float wsum = waveSum(tp);
    mx = waveMax(mx);
    if(lane == 0){ red[wid] = wsum; red[4 + wid] = mx; }
    __syncthreads();
    float c = sumU[0] * (1.0f / (float)KK) + red[0] + red[1] + red[2] + red[3];
    float m = fmaxf(fmaxf(red[4], red[5]), fmaxf(red[6], red[7]));
    m = fmaxf(0.f, m + c);

    float4 a0 = make_float4(0,0,0,0), a1 = make_float4(0,0,0,0);
    float accZ = 0.f;
    int myN = (KK - 1 - gw) / NW + 1;
    int k = 0;
    for(; k + 8 <= myN; k += 8){
      float w[8];
      #pragma unroll
      for(int r = 0; r < 8; r++)
        w[r] = s[(size_t)gw + (size_t)(k + r) * NW];
      #pragma unroll
      for(int r = 0; r < 8; r++){
        w[r] = __expf(fmaxf(w[r] + c, 0.f) - m);
        accZ += w[r];
      }
      #pragma unroll
      for(int r = 0; r < 8; r++){
        size_t row = (size_t)gw + (size_t)(k + r) * NW;
        const float4* xr = (const float4*)(x + row * MM);
        float4 x0 = xr[lane];
        float4 x1 = xr[64 + lane];
        a0.x += w[r] * x0.x; a0.y += w[r] * x0.y; a0.z += w[r] * x0.z; a0.w += w[r] * x0.w;
        a1.x += w[r] * x1.x; a1.y += w[r] * x1.y; a1.z += w[r] * x1.z; a1.w += w[r] * x1.w;
      }
    }
    for(; k < myN; k++){
      size_t row = (size_t)gw + (size_t)k * NW;
      float w = __expf(fmaxf(s[row] + c, 0.f) - m);
      accZ += w;
      const float4* xr = (const float4*)(x + row * MM);
      float4 x0 = xr[lane];
      float4 x1 = xr[64 + lane];
      a0.x += w * x0.x; a0.y += w * x0.y; a0.z += w * x0.z; a0.w += w * x0.w;
      a1.x += w * x1.x; a1.y += w * x1.y; a1.z += w * x1.z; a1.w += w * x1.w;
    }

    float zw = waveSum(accZ);
    __syncthreads();                 // red fully read above
    float4* lw4 = (float4*)lw;
    lw4[wid * 128 + lane * 2]     = a0;
    lw4[wid * 128 + lane * 2 + 1] = a1;
    if(lane == 0) red[wid] = zw;
    __syncthreads();
    int l = tid >> 2, q = tid & 3;
    float s0 = lw[0*512 + l*8 + q] + lw[1*512 + l*8 + q]
             + lw[2*512 + l*8 + q] + lw[3*512 + l*8 + q];
    float s1 = lw[0*512 + l*8 + 4 + q] + lw[1*512 + l*8 + 4 + q]
             + lw[2*512 + l*8 + 4 + q] + lw[3*512 + l*8 + 4 + q];
    part[(size_t)blockIdx.x * 512 + tid]       = s0;
    part[(size_t)blockIdx.x * 512 + 256 + tid] = s1;
    if(tid == 0)
      atomicAdd(Z, (red[0] + red[1] + red[2] + red[3]) * (1.0f / 64.0f));
  }
  gridBarrier(barB, tid);

  // ---- phase 3: reduce part[1024][512] -> acc; last block divides by Z ----
  if(blockIdx.x < NOUT){
    const float* p = part + (size_t)blockIdx.x * (NB1 / NOUT) * 512;
    float s0 = 0.f, s1 = 0.f;
    #pragma unroll 8
    for(int bb = 0; bb < NB1 / NOUT; bb++){
      s0 += p[bb * 512 + tid];
      s1 += p[bb * 512 + 256 + tid];
    }
    atomicAdd(&acc[tid],       s0);
    atomicAdd(&acc[tid + 256], s1);
    __threadfence();
    if(tid == 0) lastf = (atomicAdd(cnt, 1) == NOUT - 1) ? 1 : 0;
    __syncthreads();
    if(lastf){
      float z  = atomicAdd(Z, 0.0f);                // coherent read
      float v0r = atomicAdd(&acc[tid],       0.0f); // coherent read of atomics
      float v1r = atomicAdd(&acc[tid + 256], 0.0f);
      out[tid]       = v0r / z;
      out[tid + 256] = v1r / z;
    }
  }
}

// ---------------------------------------------------------------------------
// Legacy proven 4-kernel chain (fallback if cooperative launch is rejected).
// ---------------------------------------------------------------------------
__global__ __launch_bounds__(512) void k_vu(const float* __restrict__ W,
                                            const float* __restrict__ a,
                                            float* __restrict__ v,
                                            float* __restrict__ u){
  int j  = threadIdx.x;
  int k0 = blockIdx.x * 8;
  float pv = 0.f, pu = 0.f;
  #pragma unroll
  for(int kk = 0; kk < 8; kk++){
    float w = W[(size_t)(k0 + kk) * MM + j];
    pv += w * a[k0 + kk];
    pu += w * a[MM + k0 + kk];
  }
  atomicAdd(&v[j], pv);
  atomicAdd(&u[j], pu);
}

__global__ __launch_bounds__(256) void k_pass1(const float* __restrict__ x,
                                               const float* __restrict__ vv,
                                               const float* __restrict__ uu,
                                               float* __restrict__ s,
                                               float* __restrict__ sumU,
                                               float* __restrict__ pmax){
  __shared__ float lsum[4];
  __shared__ float lmax[4];
  int tid  = threadIdx.x;
  int lane = tid & 63;
  int wid  = tid >> 6;
  int gw   = blockIdx.x * 4 + wid;

  const float4* v4 = (const float4*)vv;
  const float4* u4 = (const float4*)uu;
  float4 v0 = v4[lane],      v1 = v4[64 + lane];
  float4 u0 = u4[lane],      u1 = u4[64 + lane];
  float accU = 0.f;
  float wmax = -3.4e38f;

  int myN = (KK - 1 - gw) / NW + 1;
  int k = 0;
  for(; k + 8 <= myN; k += 8){
    float d[8];
    #pragma unroll
    for(int r = 0; r < 8; r++){
      size_t row = (size_t)gw + (size_t)(k + r) * NW;
      const float4* xr = (const float4*)(x + row * MM);
      float4 x0 = xr[lane];
      float4 x1 = xr[64 + lane];
      d[r]  = dot8(x0, x1, v0, v1);
      accU += dot8(x0, x1, u0, u1);
    }
    #pragma unroll
    for(int off = 1; off < 64; off <<= 1){
      #pragma unroll
      for(int r = 0; r < 8; r++) d[r] += __shfl_xor(d[r], off, 64);
    }
    float m01 = fmaxf(fmaxf(d[0], d[1]), fmaxf(d[2], d[3]));
    float m23 = fmaxf(fmaxf(d[4], d[5]), fmaxf(d[6], d[7]));
    wmax = fmaxf(wmax, fmaxf(m01, m23));
    float s0 = (lane & 1) ? d[1] : d[0];
    float s1 = (lane & 1) ? d[3] : d[2];
    float s2 = (lane & 1) ? d[5] : d[4];
    float s3 = (lane & 1) ? d[7] : d[6];
    float t0 = (lane & 2) ? s1 : s0;
    float t1 = (lane & 2) ? s3 : s2;
    float rr = (lane & 4) ? t1 : t0;
    if(lane < 8) s[(size_t)gw + (size_t)(k + lane) * NW] = rr;
  }
  for(; k < myN; k++){
    size_t row = (size_t)gw + (size_t)k * NW;
    const float4* xr = (const float4*)(x + row * MM);
    float4 x0 = xr[lane];
    float4 x1 = xr[64 + lane];
    float d = dot8(x0, x1, v0, v1);
    accU += dot8(x0, x1, u0, u1);
    #pragma unroll
    for(int off = 1; off < 64; off <<= 1) d += __shfl_xor(d, off, 64);
    wmax = fmaxf(wmax, d);
    if(lane == 0) s[row] = d;
  }

  float ws_ = waveSum(accU);
  if(lane == 0){ lsum[wid] = ws_; lmax[wid] = wmax; }
  __syncthreads();
  if(tid == 0){
    atomicAdd(sumU, lsum[0] + lsum[1] + lsum[2] + lsum[3]);
    pmax[blockIdx.x] = fmaxf(fmaxf(lmax[0], lmax[1]), fmaxf(lmax[2], lmax[3]));
  }
}

__global__ __launch_bounds__(256) void k_pass2(const float* __restrict__ x,
                                               const float* __restrict__ s,
                                               const float* __restrict__ b,
                                               const float* __restrict__ a,
                                               const float* __restrict__ sumU,
                                               const float* __restrict__ pmax,
                                               float* __restrict__ part,
                                               float* __restrict__ Z){
  __shared__ float red[8];
  __shared__ float lw[2048];
  int tid  = threadIdx.x;
  int lane = tid & 63;
  int wid  = tid >> 6;
  int gw   = blockIdx.x * 4 + wid;

  float tp = b[tid]       * (a[tid]       + a[MM + tid])
           + b[tid + 256] * (a[tid + 256] + a[MM + tid + 256]);
  float mx = fmaxf(fmaxf(pmax[tid], pmax[tid + 256]),
                   fmaxf(pmax[tid + 512], pmax[tid + 768]));
  float wsum = waveSum(tp);
  mx = waveMax(mx);
  if(lane == 0){ red[wid] = wsum; red[4 + wid] = mx; }
  __syncthreads();
  float c = sumU[0] * (1.0f / (float)KK) + red[0] + red[1] + red[2] + red[3];
  float m = fmaxf(fmaxf(red[4], red[5]), fmaxf(red[6], red[7]));
  m = fmaxf(0.f, m + c);

  float4 a0 = make_float4(0,0,0,0), a1 = make_float4(0,0,0,0);
  float accZ = 0.f;
  int myN = (KK - 1 - gw) / NW + 1;
  int k = 0;
  for(; k + 8 <= myN; k += 8){
    float w[8];
    #pragma unroll
    for(int r = 0; r < 8; r++)
      w[r] = s[(size_t)gw + (size_t)(k + r) * NW];
    #pragma unroll
    for(int r = 0; r < 8; r++){
      w[r] = __expf(fmaxf(w[r] + c, 0.f) - m);
      accZ += w[r];
    }
    #pragma unroll
    for(int r = 0; r < 8; r++){
      size_t row = (size_t)gw + (size_t)(k + r) * NW;
      const float4* xr = (const float4*)(x + row * MM);
      float4 x0 = xr[lane];
      float4 x1 = xr[64 + lane];
      a0.x += w[r] * x0.x; a0.y += w[r] * x0.y; a0.z += w[r] * x0.z; a0.w += w[r] * x0.w;
      a1.x += w[r] * x1.x; a1.y += w[r] * x1.y; a1.z += w[r] * x1.z; a1.w += w[r] * x1.w;
    }
  }
  for(; k < myN; k++){
    size_t row = (size_t)gw + (size_t)k * NW;
    float w = __expf(fmaxf(s[row] + c, 0.f) - m);
    accZ += w;
    const float4* xr = (const float4*)(x + row * MM);
    float4 x0 = xr[lane];
    float4 x1 = xr[64 + lane];
    a0.x += w * x0.x; a0.y += w * x0.y; a0.z += w * x0.z; a0.w += w * x0.w;
    a1.x += w * x1.x; a1.y += w * x1.y; a1.z += w * x1.z; a1.w += w * x1.w;
  }

  float zw = waveSum(accZ);
  __syncthreads();
  float4* lw4 = (float4*)lw;
  lw4[wid * 128 + lane * 2]     = a0;
  lw4[wid * 128 + lane * 2 + 1] = a1;
  if(lane == 0) red[wid] = zw;
  __syncthreads();
  int l = tid >> 2, q = tid & 3;
  float s0 = lw[0*512 + l*8 + q] + lw[1*512 + l*8 + q]
           + lw[2*512 + l*8 + q] + lw[3*512 + l*8 + q];
  float s1 = lw[0*512 + l*8 + 4 + q] + lw[1*512 + l*8 + 4 + q]
           + lw[2*512 + l*8 + 4 + q] + lw[3*512 + l*8 + 4 + q];
  part[(size_t)blockIdx.x * 512 + tid]       = s0;
  part[(size_t)blockIdx.x * 512 + 256 + tid] = s1;
  if(tid == 0)
    atomicAdd(Z, (red[0] + red[1] + red[2] + red[3]) * (1.0f / 64.0f));
}

__global__ __launch_bounds__(256) void k_out(const float* __restrict__ part,
                                             float* __restrict__ acc,
                                             const float* __restrict__ Z,
                                             int* __restrict__ cnt,
                                             float* __restrict__ out){
  __shared__ int lastf;
  int tid = threadIdx.x;
  const float* p = part + (size_t)blockIdx.x * (NB1 / NOUT) * 512;
  float s0 = 0.f, s1 = 0.f;
  #pragma unroll 8
  for(int bb = 0; bb < NB1 / NOUT; bb++){
    s0 += p[bb * 512 + tid];
    s1 += p[bb * 512 + 256 + tid];
  }
  atomicAdd(&acc[tid],       s0);
  atomicAdd(&acc[tid + 256], s1);
  __threadfence();
  if(tid == 0) lastf = (atomicAdd(cnt, 1) == NOUT - 1) ? 1 : 0;
  __syncthreads();
  if(lastf){
    float z = Z[0];
    float v0 = atomicAdd(&acc[tid],       0.0f);
    float v1 = atomicAdd(&acc[tid + 256], 0.0f);
    out[tid]       = v0 / z;
    out[tid + 256] = v1 / z;
  }
}

extern "C" void kernel_launch(void* const* d_in, const int* in_sizes, int n_in,
                              void* d_out, int out_size, void* d_ws, size_t ws_size,
                              hipStream_t stream) {
  const float* x = (const float*)d_in[0];
  const float* W = (const float*)d_in[1];
  const float* b = (const float*)d_in[2];
  const float* a = (const float*)d_in[3];
  float* ws  = (float*)d_ws;
  float* out = (float*)d_out;

  hipMemsetAsync(ws, 0, 2048 * sizeof(float), stream);  // v,u,sumU,Z,cnt,bars,acc

  void* args[] = {(void*)&x, (void*)&W, (void*)&b, (void*)&a, (void*)&ws, (void*)&out};
  hipError_t err = hipLaunchCooperativeKernel((const void*)k_fused,
                                              dim3(NB1), dim3(256),
                                              args, 0, stream);
  if(err != hipSuccess){
    // Fallback: proven 4-kernel chain (identical numerics).
    float* v    = ws;
    float* u    = ws + 512;
    float* sumU = ws + 1024;
    float* Z    = ws + 1025;
    int*   cnt  = (int*)(ws + 1026);
    float* acc  = ws + 1536;
    float* pmax = ws + 2048;
    float* s    = ws + 4096;
    float* part = ws + 131072;
    k_vu   <<<64,   512, 0, stream>>>(W, a, v, u);
    k_pass1<<<NB1,  256, 0, stream>>>(x, v, u, s, sumU, pmax);
    k_pass2<<<NB1,  256, 0, stream>>>(x, s, b, a, sumU, pmax, part, Z);
    k_out  <<<NOUT, 256, 0, stream>>>(part, acc, Z, cnt, out);
  }
}

// Round 2
// 338.022 us; speedup vs baseline: 2.4449x; 2.4449x over previous
//
#include <hip/hip_runtime.h>
#include <math.h>

#define MM 512
#define KK 100000
#define NB1 1024               // pass1/pass2 blocks (4 waves each -> 4096 waves)
#define NW  (NB1 * 4)          // total waves in pass kernels
#define SSTR 32                // per-wave s stride (myN <= 25 < 32), contiguous layout
#define NOUT 16                // k_out blocks

// ws float layout:
// [0..512)     v = W^T a1
// [512..1024)  u = W^T a2
// [1024]       sumU = sum_i x_i . u
// [1025]       Z    = sum_i exp(relu(s_i+c)-m) (atomic-accumulated, /64)
// [1026]       done-counter for k_out (int)
// [1536..2048) acc (k_out cross-block accumulator)
// [2048..3072) pmax (per-block partial max of s; written unconditionally)
// [4096..135168)   s: per-wave CONTIGUOUS, s[gw*32 + k]  (4096 waves x 32)
// [196608..720896) part: per-block unnormalized colsums, part[b][512]
// memset zeroes the first 2048 floats (v,u,sumU,Z,counter,acc).

__device__ inline float waveSum(float v){
  #pragma unroll
  for(int off = 32; off > 0; off >>= 1) v += __shfl_down(v, off, 64);
  return v;   // total in lane 0
}
__device__ inline float waveMax(float v){
  #pragma unroll
  for(int off = 32; off > 0; off >>= 1) v = fmaxf(v, __shfl_down(v, off, 64));
  return v;
}
__device__ inline float dot8(float4 x0, float4 x1, float4 v0, float4 v1){
  return x0.x*v0.x + x0.y*v0.y + x0.z*v0.z + x0.w*v0.w
       + x1.x*v1.x + x1.y*v1.y + x1.z*v1.z + x1.w*v1.w;
}

// v_j = sum_k W[k,j] a1[k] ; u_j = sum_k W[k,j] a2[k]
__global__ __launch_bounds__(512) void k_vu(const float* __restrict__ W,
                                            const float* __restrict__ a,
                                            float* __restrict__ v,
                                            float* __restrict__ u){
  int j  = threadIdx.x;
  int k0 = blockIdx.x * 8;
  float pv = 0.f, pu = 0.f;
  #pragma unroll
  for(int kk = 0; kk < 8; kk++){
    float w = W[(size_t)(k0 + kk) * MM + j];
    pv += w * a[k0 + kk];
    pu += w * a[MM + k0 + kk];
  }
  atomicAdd(&v[j], pv);
  atomicAdd(&u[j], pu);
}

// Pass 1: s_i = x_i.v (8-row batched butterfly reduce), sumU += x_i.u,
// per-block max of s.  s stored per-wave contiguous: s[gw*SSTR + k].
__global__ __launch_bounds__(256) void k_pass1(const float* __restrict__ x,
                                               const float* __restrict__ vv,
                                               const float* __restrict__ uu,
                                               float* __restrict__ s,
                                               float* __restrict__ sumU,
                                               float* __restrict__ pmax){
  __shared__ float lsum[4];
  __shared__ float lmax[4];
  int tid  = threadIdx.x;
  int lane = tid & 63;
  int wid  = tid >> 6;
  int gw   = blockIdx.x * 4 + wid;

  const float4* v4 = (const float4*)vv;
  const float4* u4 = (const float4*)uu;
  float4 v0 = v4[lane],      v1 = v4[64 + lane];
  float4 u0 = u4[lane],      u1 = u4[64 + lane];
  float accU = 0.f;
  float wmax = -3.4e38f;

  int myN = (KK - 1 - gw) / NW + 1;   // rows this wave owns (24 or 25)
  int k = 0;
  for(; k + 8 <= myN; k += 8){
    float d[8];
    #pragma unroll
    for(int r = 0; r < 8; r++){
      size_t row = (size_t)gw + (size_t)(k + r) * NW;
      const float4* xr = (const float4*)(x + row * MM);
      float4 x0 = xr[lane];
      float4 x1 = xr[64 + lane];
      d[r]  = dot8(x0, x1, v0, v1);
      accU += dot8(x0, x1, u0, u1);
    }
    #pragma unroll
    for(int off = 1; off < 64; off <<= 1){
      #pragma unroll
      for(int r = 0; r < 8; r++) d[r] += __shfl_xor(d[r], off, 64);
    }
    float m01 = fmaxf(fmaxf(d[0], d[1]), fmaxf(d[2], d[3]));
    float m23 = fmaxf(fmaxf(d[4], d[5]), fmaxf(d[6], d[7]));
    wmax = fmaxf(wmax, fmaxf(m01, m23));
    float s0 = (lane & 1) ? d[1] : d[0];
    float s1 = (lane & 1) ? d[3] : d[2];
    float s2 = (lane & 1) ? d[5] : d[4];
    float s3 = (lane & 1) ? d[7] : d[6];
    float t0 = (lane & 2) ? s1 : s0;
    float t1 = (lane & 2) ? s3 : s2;
    float rr = (lane & 4) ? t1 : t0;
    if(lane < 8) s[gw * SSTR + k + lane] = rr;   // contiguous 32B burst
  }
  for(; k < myN; k++){
    size_t row = (size_t)gw + (size_t)k * NW;
    const float4* xr = (const float4*)(x + row * MM);
    float4 x0 = xr[lane];
    float4 x1 = xr[64 + lane];
    float d = dot8(x0, x1, v0, v1);
    accU += dot8(x0, x1, u0, u1);
    #pragma unroll
    for(int off = 1; off < 64; off <<= 1) d += __shfl_xor(d, off, 64);
    wmax = fmaxf(wmax, d);
    if(lane == 0) s[gw * SSTR + k] = d;
  }

  float ws_ = waveSum(accU);
  if(lane == 0){ lsum[wid] = ws_; lmax[wid] = wmax; }
  __syncthreads();
  if(tid == 0){
    atomicAdd(sumU, lsum[0] + lsum[1] + lsum[2] + lsum[3]);
    pmax[blockIdx.x] = fmaxf(fmaxf(lmax[0], lmax[1]), fmaxf(lmax[2], lmax[3]));
  }
}

// Pass 2 (+mid folded): each block computes c,m itself, streams its rows,
// writes per-block colsum partials to part[b][512] (NO global atomics),
// one atomicAdd into Z per block.
__global__ __launch_bounds__(256) void k_pass2(const float* __restrict__ x,
                                               const float* __restrict__ s,
                                               const float* __restrict__ b,
                                               const float* __restrict__ a,
                                               const float* __restrict__ sumU,
                                               const float* __restrict__ pmax,
                                               float* __restrict__ part,
                                               float* __restrict__ Z){
  __shared__ float red[8];
  __shared__ float lw[2048];   // 4 waves x 64 lanes x 8 cols
  int tid  = threadIdx.x;
  int lane = tid & 63;
  int wid  = tid >> 6;
  int gw   = blockIdx.x * 4 + wid;

  // ---- prologue: c = b.(a1+a2) + sumU/K ; m = max(0, max_i s_i + c) ----
  float tp = b[tid]       * (a[tid]       + a[MM + tid])
           + b[tid + 256] * (a[tid + 256] + a[MM + tid + 256]);
  float mx = fmaxf(fmaxf(pmax[tid], pmax[tid + 256]),
                   fmaxf(pmax[tid + 512], pmax[tid + 768]));
  float wsum = waveSum(tp);
  mx = waveMax(mx);
  if(lane == 0){ red[wid] = wsum; red[4 + wid] = mx; }
  __syncthreads();
  float c = sumU[0] * (1.0f / (float)KK) + red[0] + red[1] + red[2] + red[3];
  float m = fmaxf(fmaxf(red[4], red[5]), fmaxf(red[6], red[7]));
  m = fmaxf(0.f, m + c);

  // ---- main streaming loop (8-row batched) ----
  float4 a0 = make_float4(0,0,0,0), a1 = make_float4(0,0,0,0);
  float accZ = 0.f;
  int myN = (KK - 1 - gw) / NW + 1;
  int k = 0;
  for(; k + 8 <= myN; k += 8){
    // 8 contiguous per-wave s values: two aligned float4 loads
    const float4* s4 = (const float4*)(s + gw * SSTR + k);
    float4 wa = s4[0], wb = s4[1];
    float w[8] = {wa.x, wa.y, wa.z, wa.w, wb.x, wb.y, wb.z, wb.w};
    #pragma unroll
    for(int r = 0; r < 8; r++){
      w[r] = __expf(fmaxf(w[r] + c, 0.f) - m);
      accZ += w[r];
    }
    #pragma unroll
    for(int r = 0; r < 8; r++){
      size_t row = (size_t)gw + (size_t)(k + r) * NW;
      const float4* xr = (const float4*)(x + row * MM);
      float4 x0 = xr[lane];
      float4 x1 = xr[64 + lane];
      a0.x += w[r] * x0.x; a0.y += w[r] * x0.y; a0.z += w[r] * x0.z; a0.w += w[r] * x0.w;
      a1.x += w[r] * x1.x; a1.y += w[r] * x1.y; a1.z += w[r] * x1.z; a1.w += w[r] * x1.w;
    }
  }
  for(; k < myN; k++){
    size_t row = (size_t)gw + (size_t)k * NW;
    float w = __expf(fmaxf(s[gw * SSTR + k] + c, 0.f) - m);
    accZ += w;
    const float4* xr = (const float4*)(x + row * MM);
    float4 x0 = xr[lane];
    float4 x1 = xr[64 + lane];
    a0.x += w * x0.x; a0.y += w * x0.y; a0.z += w * x0.z; a0.w += w * x0.w;
    a1.x += w * x1.x; a1.y += w * x1.y; a1.z += w * x1.z; a1.w += w * x1.w;
  }

  // ---- tail: cross-wave sum via plain LDS, coalesced non-atomic output ----
  float zw = waveSum(accZ);
  __syncthreads();                 // red's first use fully read above
  float4* lw4 = (float4*)lw;
  lw4[wid * 128 + lane * 2]     = a0;   // lane l holds cols 4l+q   (q=0..3)
  lw4[wid * 128 + lane * 2 + 1] = a1;   // and cols 256+4l+q
  if(lane == 0) red[wid] = zw;
  __syncthreads();
  int l = tid >> 2, q = tid & 3;
  float s0 = lw[0*512 + l*8 + q] + lw[1*512 + l*8 + q]
           + lw[2*512 + l*8 + q] + lw[3*512 + l*8 + q];
  float s1 = lw[0*512 + l*8 + 4 + q] + lw[1*512 + l*8 + 4 + q]
           + lw[2*512 + l*8 + 4 + q] + lw[3*512 + l*8 + 4 + q];
  part[(size_t)blockIdx.x * 512 + tid]       = s0;
  part[(size_t)blockIdx.x * 512 + 256 + tid] = s1;
  if(tid == 0)
    atomicAdd(Z, (red[0] + red[1] + red[2] + red[3]) * (1.0f / 64.0f));
}

// Reduce part[1024][512] -> acc, last block divides by Z and writes out.
__global__ __launch_bounds__(256) void k_out(const float* __restrict__ part,
                                             float* __restrict__ acc,
                                             const float* __restrict__ Z,
                                             int* __restrict__ cnt,
                                             float* __restrict__ out){
  __shared__ int lastf;
  int tid = threadIdx.x;
  const float* p = part + (size_t)blockIdx.x * (NB1 / NOUT) * 512;
  float s0 = 0.f, s1 = 0.f;
  #pragma unroll 8
  for(int bb = 0; bb < NB1 / NOUT; bb++){
    s0 += p[bb * 512 + tid];
    s1 += p[bb * 512 + 256 + tid];
  }
  atomicAdd(&acc[tid],       s0);
  atomicAdd(&acc[tid + 256], s1);
  __threadfence();
  if(tid == 0) lastf = (atomicAdd(cnt, 1) == NOUT - 1) ? 1 : 0;
  __syncthreads();
  if(lastf){
    float z = Z[0];   // written by previous dispatch — safe plain read
    float v0 = atomicAdd(&acc[tid],       0.0f);  // coherent read of atomics
    float v1 = atomicAdd(&acc[tid + 256], 0.0f);
    out[tid]       = v0 / z;
    out[tid + 256] = v1 / z;
  }
}

extern "C" void kernel_launch(void* const* d_in, const int* in_sizes, int n_in,
                              void* d_out, int out_size, void* d_ws, size_t ws_size,
                              hipStream_t stream) {
  const float* x = (const float*)d_in[0];
  const float* W = (const float*)d_in[1];
  const float* b = (const float*)d_in[2];
  const float* a = (const float*)d_in[3];
  float* ws  = (float*)d_ws;
  float* out = (float*)d_out;

  float* v    = ws;
  float* u    = ws + 512;
  float* sumU = ws + 1024;
  float* Z    = ws + 1025;
  int*   cnt  = (int*)(ws + 1026);
  float* acc  = ws + 1536;
  float* pmax = ws + 2048;
  float* s    = ws + 4096;
  float* part = ws + 196608;

  hipMemsetAsync(ws, 0, 2048 * sizeof(float), stream);  // v,u,sumU,Z,cnt,acc

  k_vu   <<<64,   512, 0, stream>>>(W, a, v, u);
  k_pass1<<<NB1,  256, 0, stream>>>(x, v, u, s, sumU, pmax);
  k_pass2<<<NB1,  256, 0, stream>>>(x, s, b, a, sumU, pmax, part, Z);
  k_out  <<<NOUT, 256, 0, stream>>>(part, acc, Z, cnt, out);
}

// Round 3
// 326.692 us; speedup vs baseline: 2.5297x; 1.0347x over previous
//
#include <hip/hip_runtime.h>
#include <math.h>

#define MM 512
#define KK 100000
#define NB1 1024               // pass1/corr blocks (4 waves each -> 4096 waves)
#define NW  (NB1 * 4)          // total waves in pass kernels
#define SSTR 32                // per-wave s stride (myN <= 25 < 32), contiguous layout
#define NOUT 16                // k_out blocks

// ws float layout:
// [0..512)     v = W^T a1
// [512..1024)  u = W^T a2
// [1024]       sumU = sum_i x_i . u
// [1025]       Z    (atomic-accumulated, raw)
// [1026]       done-counter for k_out (int)
// [1536..2048) acc (k_out cross-block accumulator)
// [2048..3072) pmax (per-block m_blk = max_i s_i; written unconditionally)
// [3072..4096) zpart (per-block Ez_blk; written unconditionally)
// [4096..135168)   s: per-wave CONTIGUOUS, s[gw*32 + k]  (4096 waves x 32)
// [196608..720896) part: per-block E partials (pass1), rescaled+corrected (k_corr)
// memset zeroes the first 2048 floats (v,u,sumU,Z,counter,acc).

__device__ inline float waveSum(float v){
  #pragma unroll
  for(int off = 32; off > 0; off >>= 1) v += __shfl_down(v, off, 64);
  return v;   // total in lane 0
}
__device__ inline float waveMax(float v){
  #pragma unroll
  for(int off = 32; off > 0; off >>= 1) v = fmaxf(v, __shfl_down(v, off, 64));
  return v;
}
__device__ inline float dot8(float4 x0, float4 x1, float4 v0, float4 v1){
  return x0.x*v0.x + x0.y*v0.y + x0.z*v0.z + x0.w*v0.w
       + x1.x*v1.x + x1.y*v1.y + x1.z*v1.z + x1.w*v1.w;
}
__device__ inline void fma4(float4& acc, float w, float4 x){
  acc.x += w * x.x; acc.y += w * x.y; acc.z += w * x.z; acc.w += w * x.w;
}
__device__ inline void scale4(float4& v, float s){
  v.x *= s; v.y *= s; v.z *= s; v.w *= s;
}

// v_j = sum_k W[k,j] a1[k] ; u_j = sum_k W[k,j] a2[k]
__global__ __launch_bounds__(512) void k_vu(const float* __restrict__ W,
                                            const float* __restrict__ a,
                                            float* __restrict__ v,
                                            float* __restrict__ u){
  int j  = threadIdx.x;
  int k0 = blockIdx.x * 8;
  float pv = 0.f, pu = 0.f;
  #pragma unroll
  for(int kk = 0; kk < 8; kk++){
    float w = W[(size_t)(k0 + kk) * MM + j];
    pv += w * a[k0 + kk];
    pu += w * a[MM + k0 + kk];
  }
  atomicAdd(&v[j], pv);
  atomicAdd(&u[j], pu);
}

// Pass 1 (online): per row compute s_i = x_i.v (4-row batched butterfly),
// sumU += x_i.u, and ONLINE accumulate E = sum_i exp(s_i - m_w) * x_i with
// running per-wave max m_w (flash-style rescale).  Cross-wave combine to
// part[b][512] at block max m_blk; also write pmax[b]=m_blk, zpart[b]=Ez_blk.
__global__ __launch_bounds__(256) void k_pass1o(const float* __restrict__ x,
                                                const float* __restrict__ vv,
                                                const float* __restrict__ uu,
                                                float* __restrict__ s,
                                                float* __restrict__ sumU,
                                                float* __restrict__ pmax,
                                                float* __restrict__ part,
                                                float* __restrict__ zpart){
  __shared__ float lsum[4];
  __shared__ float lmax[4];
  __shared__ float ezs[4];
  __shared__ float lw[2048];   // 4 waves x 64 lanes x 8 cols
  int tid  = threadIdx.x;
  int lane = tid & 63;
  int wid  = tid >> 6;
  int gw   = blockIdx.x * 4 + wid;

  const float4* v4 = (const float4*)vv;
  const float4* u4 = (const float4*)uu;
  float4 v0 = v4[lane],      v1 = v4[64 + lane];
  float4 u0 = u4[lane],      u1 = u4[64 + lane];
  float accU = 0.f;
  float m_w  = -3.4e38f;
  float Ez   = 0.f;
  float4 E0 = make_float4(0,0,0,0), E1 = make_float4(0,0,0,0);

  int myN = (KK - 1 - gw) / NW + 1;   // rows this wave owns (24 or 25)
  int k = 0;
  for(; k + 4 <= myN; k += 4){
    size_t r0 = (size_t)gw + (size_t)(k + 0) * NW;
    size_t r1 = (size_t)gw + (size_t)(k + 1) * NW;
    size_t r2 = (size_t)gw + (size_t)(k + 2) * NW;
    size_t r3 = (size_t)gw + (size_t)(k + 3) * NW;
    const float4* pa = (const float4*)(x + r0 * MM);
    const float4* pb = (const float4*)(x + r1 * MM);
    const float4* pc = (const float4*)(x + r2 * MM);
    const float4* pd = (const float4*)(x + r3 * MM);
    float4 xa0 = pa[lane], xa1 = pa[64 + lane];
    float4 xb0 = pb[lane], xb1 = pb[64 + lane];
    float4 xc0 = pc[lane], xc1 = pc[64 + lane];
    float4 xd0 = pd[lane], xd1 = pd[64 + lane];
    float d0 = dot8(xa0, xa1, v0, v1);  accU += dot8(xa0, xa1, u0, u1);
    float d1 = dot8(xb0, xb1, v0, v1);  accU += dot8(xb0, xb1, u0, u1);
    float d2 = dot8(xc0, xc1, v0, v1);  accU += dot8(xc0, xc1, u0, u1);
    float d3 = dot8(xd0, xd1, v0, v1);  accU += dot8(xd0, xd1, u0, u1);
    #pragma unroll
    for(int off = 1; off < 64; off <<= 1){
      d0 += __shfl_xor(d0, off, 64);
      d1 += __shfl_xor(d1, off, 64);
      d2 += __shfl_xor(d2, off, 64);
      d3 += __shfl_xor(d3, off, 64);
    }
    // online max update (wave-uniform: d* identical in all lanes)
    float g = fmaxf(fmaxf(d0, d1), fmaxf(d2, d3));
    if(g > m_w){
      float sc = __expf(m_w - g);     // exp(-inf)=0 on first group: E stays 0
      scale4(E0, sc); scale4(E1, sc); Ez *= sc;
      m_w = g;
    }
    float w0 = __expf(d0 - m_w);
    float w1 = __expf(d1 - m_w);
    float w2 = __expf(d2 - m_w);
    float w3 = __expf(d3 - m_w);
    Ez += w0 + w1 + w2 + w3;
    fma4(E0, w0, xa0); fma4(E1, w0, xa1);
    fma4(E0, w1, xb0); fma4(E1, w1, xb1);
    fma4(E0, w2, xc0); fma4(E1, w2, xc1);
    fma4(E0, w3, xd0); fma4(E1, w3, xd1);
    // store s (lanes 0..3, contiguous 16B)
    float s0 = (lane & 1) ? d1 : d0;
    float s1 = (lane & 1) ? d3 : d2;
    float rr = (lane & 2) ? s1 : s0;
    if(lane < 4) s[gw * SSTR + k + lane] = rr;
  }
  for(; k < myN; k++){
    size_t row = (size_t)gw + (size_t)k * NW;
    const float4* xr = (const float4*)(x + row * MM);
    float4 x0 = xr[lane];
    float4 x1 = xr[64 + lane];
    float d = dot8(x0, x1, v0, v1);
    accU += dot8(x0, x1, u0, u1);
    #pragma unroll
    for(int off = 1; off < 64; off <<= 1) d += __shfl_xor(d, off, 64);
    if(d > m_w){
      float sc = __expf(m_w - d);
      scale4(E0, sc); scale4(E1, sc); Ez *= sc;
      m_w = d;
    }
    float w = __expf(d - m_w);
    Ez += w;
    fma4(E0, w, x0); fma4(E1, w, x1);
    if(lane == 0) s[gw * SSTR + k] = d;
  }

  // ---- tail: rescale to block max, cross-wave combine, write partials ----
  float us = waveSum(accU);
  if(lane == 0){ lsum[wid] = us; lmax[wid] = m_w; }
  __syncthreads();
  float m_blk = fmaxf(fmaxf(lmax[0], lmax[1]), fmaxf(lmax[2], lmax[3]));
  float sc2 = __expf(m_w - m_blk);    // wave-uniform
  scale4(E0, sc2); scale4(E1, sc2);
  if(lane == 0) ezs[wid] = Ez * sc2;
  float4* lw4 = (float4*)lw;
  lw4[wid * 128 + lane * 2]     = E0;   // lane l holds cols 4l+q
  lw4[wid * 128 + lane * 2 + 1] = E1;   // and cols 256+4l+q
  __syncthreads();
  int l = tid >> 2, q = tid & 3;
  float o0 = lw[0*512 + l*8 + q] + lw[1*512 + l*8 + q]
           + lw[2*512 + l*8 + q] + lw[3*512 + l*8 + q];
  float o1 = lw[0*512 + l*8 + 4 + q] + lw[1*512 + l*8 + 4 + q]
           + lw[2*512 + l*8 + 4 + q] + lw[3*512 + l*8 + 4 + q];
  part[(size_t)blockIdx.x * 512 + tid]       = o0;
  part[(size_t)blockIdx.x * 512 + 256 + tid] = o1;
  if(tid == 0){
    atomicAdd(sumU, lsum[0] + lsum[1] + lsum[2] + lsum[3]);
    pmax[blockIdx.x]  = m_blk;
    zpart[blockIdx.x] = ezs[0] + ezs[1] + ezs[2] + ezs[3];
  }
}

// Correction pass: compute c, M; re-read ONLY clipped rows (s_i + c < 0),
// accumulate C = sum_clip (e^-M - e^(t-M)) x_i; rescale this block's E
// partial by e^(c - M + m_blk) and add C in place; accumulate Z.
__global__ __launch_bounds__(256) void k_corr(const float* __restrict__ x,
                                              const float* __restrict__ s,
                                              const float* __restrict__ b,
                                              const float* __restrict__ a,
                                              const float* __restrict__ sumU,
                                              const float* __restrict__ pmax,
                                              float* __restrict__ part,
                                              const float* __restrict__ zpart,
                                              float* __restrict__ Z){
  __shared__ float red[8];
  __shared__ float czs[4];
  __shared__ float lw[2048];
  int tid  = threadIdx.x;
  int lane = tid & 63;
  int wid  = tid >> 6;
  int gw   = blockIdx.x * 4 + wid;

  // ---- prologue: c = b.(a1+a2) + sumU/K ; M = max(0, max_i s_i + c) ----
  float tp = b[tid]       * (a[tid]       + a[MM + tid])
           + b[tid + 256] * (a[tid + 256] + a[MM + tid + 256]);
  float mx = fmaxf(fmaxf(pmax[tid], pmax[tid + 256]),
                   fmaxf(pmax[tid + 512], pmax[tid + 768]));
  float wsum = waveSum(tp);
  mx = waveMax(mx);
  if(lane == 0){ red[wid] = wsum; red[4 + wid] = mx; }
  __syncthreads();
  float c  = sumU[0] * (1.0f / (float)KK) + red[0] + red[1] + red[2] + red[3];
  float mg = fmaxf(fmaxf(red[4], red[5]), fmaxf(red[6], red[7]));
  float M  = fmaxf(0.f, mg + c);
  float eM = __expf(-M);

  // ---- clipped-row loop (wave-uniform branch; ~50% of rows) ----
  float4 C0 = make_float4(0,0,0,0), C1 = make_float4(0,0,0,0);
  float Cz = 0.f;
  int myN = (KK - 1 - gw) / NW + 1;
  const float4* s4 = (const float4*)(s + gw * SSTR);
  #pragma unroll
  for(int g2 = 0; g2 < 7; g2++){
    int kb = g2 * 4;
    if(kb >= myN) break;
    float4 sv = s4[g2];
    {
      int k = kb + 0;
      float t = sv.x + c;
      if(k < myN && t < 0.f){
        float kap = eM - __expf(t - M);
        size_t row = (size_t)gw + (size_t)k * NW;
        const float4* xr = (const float4*)(x + row * MM);
        float4 x0 = xr[lane], x1 = xr[64 + lane];
        fma4(C0, kap, x0); fma4(C1, kap, x1); Cz += kap;
      }
    }
    {
      int k = kb + 1;
      float t = sv.y + c;
      if(k < myN && t < 0.f){
        float kap = eM - __expf(t - M);
        size_t row = (size_t)gw + (size_t)k * NW;
        const float4* xr = (const float4*)(x + row * MM);
        float4 x0 = xr[lane], x1 = xr[64 + lane];
        fma4(C0, kap, x0); fma4(C1, kap, x1); Cz += kap;
      }
    }
    {
      int k = kb + 2;
      float t = sv.z + c;
      if(k < myN && t < 0.f){
        float kap = eM - __expf(t - M);
        size_t row = (size_t)gw + (size_t)k * NW;
        const float4* xr = (const float4*)(x + row * MM);
        float4 x0 = xr[lane], x1 = xr[64 + lane];
        fma4(C0, kap, x0); fma4(C1, kap, x1); Cz += kap;
      }
    }
    {
      int k = kb + 3;
      float t = sv.w + c;
      if(k < myN && t < 0.f){
        float kap = eM - __expf(t - M);
        size_t row = (size_t)gw + (size_t)k * NW;
        const float4* xr = (const float4*)(x + row * MM);
        float4 x0 = xr[lane], x1 = xr[64 + lane];
        fma4(C0, kap, x0); fma4(C1, kap, x1); Cz += kap;
      }
    }
  }

  // ---- combine C across waves; rescale+correct part in place; Z ----
  __syncthreads();                 // red fully consumed above
  float4* lw4 = (float4*)lw;
  lw4[wid * 128 + lane * 2]     = C0;
  lw4[wid * 128 + lane * 2 + 1] = C1;
  if(lane == 0) czs[wid] = Cz;     // Cz identical across lanes (uniform kap)
  __syncthreads();
  int l = tid >> 2, q = tid & 3;
  float o0 = lw[0*512 + l*8 + q] + lw[1*512 + l*8 + q]
           + lw[2*512 + l*8 + q] + lw[3*512 + l*8 + q];
  float o1 = lw[0*512 + l*8 + 4 + q] + lw[1*512 + l*8 + 4 + q]
           + lw[2*512 + l*8 + 4 + q] + lw[3*512 + l*8 + 4 + q];
  float scB = __expf(c - M + pmax[blockIdx.x]);   // <= 1 by construction
  size_t base = (size_t)blockIdx.x * 512;
  part[base + tid]       = part[base + tid]       * scB + o0;
  part[base + 256 + tid] = part[base + 256 + tid] * scB + o1;
  if(tid == 0)
    atomicAdd(Z, czs[0] + czs[1] + czs[2] + czs[3] + scB * zpart[blockIdx.x]);
}

// Reduce part[1024][512] -> acc, last block divides by Z and writes out.
__global__ __launch_bounds__(256) void k_out(const float* __restrict__ part,
                                             float* __restrict__ acc,
                                             const float* __restrict__ Z,
                                             int* __restrict__ cnt,
                                             float* __restrict__ out){
  __shared__ int lastf;
  int tid = threadIdx.x;
  const float* p = part + (size_t)blockIdx.x * (NB1 / NOUT) * 512;
  float s0 = 0.f, s1 = 0.f;
  #pragma unroll 8
  for(int bb = 0; bb < NB1 / NOUT; bb++){
    s0 += p[bb * 512 + tid];
    s1 += p[bb * 512 + 256 + tid];
  }
  atomicAdd(&acc[tid],       s0);
  atomicAdd(&acc[tid + 256], s1);
  __threadfence();
  if(tid == 0) lastf = (atomicAdd(cnt, 1) == NOUT - 1) ? 1 : 0;
  __syncthreads();
  if(lastf){
    float z = Z[0];   // written by previous dispatch — safe plain read
    float v0 = atomicAdd(&acc[tid],       0.0f);  // coherent read of atomics
    float v1 = atomicAdd(&acc[tid + 256], 0.0f);
    out[tid]       = v0 / z;
    out[tid + 256] = v1 / z;
  }
}

extern "C" void kernel_launch(void* const* d_in, const int* in_sizes, int n_in,
                              void* d_out, int out_size, void* d_ws, size_t ws_size,
                              hipStream_t stream) {
  const float* x = (const float*)d_in[0];
  const float* W = (const float*)d_in[1];
  const float* b = (const float*)d_in[2];
  const float* a = (const float*)d_in[3];
  float* ws  = (float*)d_ws;
  float* out = (float*)d_out;

  float* v     = ws;
  float* u     = ws + 512;
  float* sumU  = ws + 1024;
  float* Z     = ws + 1025;
  int*   cnt   = (int*)(ws + 1026);
  float* acc   = ws + 1536;
  float* pmax  = ws + 2048;
  float* zpart = ws + 3072;
  float* s     = ws + 4096;
  float* part  = ws + 196608;

  hipMemsetAsync(ws, 0, 2048 * sizeof(float), stream);  // v,u,sumU,Z,cnt,acc

  k_vu    <<<64,   512, 0, stream>>>(W, a, v, u);
  k_pass1o<<<NB1,  256, 0, stream>>>(x, v, u, s, sumU, pmax, part, zpart);
  k_corr  <<<NB1,  256, 0, stream>>>(x, s, b, a, sumU, pmax, part, zpart, Z);
  k_out   <<<NOUT, 256, 0, stream>>>(part, acc, Z, cnt, out);
}